// Round 12
// baseline (204.419 us; speedup 1.0000x reference)
//
#include <hip/hip_runtime.h>
#include <hip/hip_bf16.h>

// Problem: B=2, S=2048, C=U=1024, H=16, dh=64. I/O FP32.
// 4 dispatches: prep (cast X->bf16 + transpose/cast W->bf16 + zero stats),
// QKV GEMM (m97-style staging; Q pre-scaled; V written directly in [b,h,d,s]),
// flash attention (dual q-tile per block: waves own 32 q rows across paired
// tiles (p,31-p) sharing staged K/V -> 2x MFMA per LDS byte; dbuf LDS,
// offset-free exp2 softmax, fused residual(bf16)+LN-stats), LN apply.

typedef __bf16 bf16_t;
typedef __bf16 bf16x8 __attribute__((ext_vector_type(8)));
typedef __bf16 bf16x4 __attribute__((ext_vector_type(4)));
typedef _Float16 f16_t;
typedef _Float16 f16x2 __attribute__((ext_vector_type(2)));
typedef _Float16 f16x4 __attribute__((ext_vector_type(4)));
typedef _Float16 f16x8 __attribute__((ext_vector_type(8)));
typedef float f32x4 __attribute__((ext_vector_type(4)));

constexpr int Bsz = 2;
constexpr int Seq = 2048;
constexpr int Cdim = 1024;   // == U
constexpr int Udim = 1024;
constexpr int Hn = 16;
constexpr int Dh = 64;
constexpr int Mrows = Bsz * Seq;          // 4096
constexpr int PerBatch = Seq * Udim;      // 2^21
constexpr float SCLQ = 0.125f * 1.44269504088896340736f;  // /sqrt(dh) * log2e

// async global->LDS, 16B per lane; LDS dest = wave-uniform base + lane*16
__device__ __forceinline__ void gload16(const void* g, void* l)
{
    __builtin_amdgcn_global_load_lds(
        (const __attribute__((address_space(1))) void*)g,
        (__attribute__((address_space(3))) void*)l, 16, 0, 0);
}

// pack two f32 -> f16x2 via v_cvt_pkrtz
__device__ __forceinline__ f16x2 pkrtz(float a, float b)
{
    return __builtin_bit_cast(f16x2, __builtin_amdgcn_cvt_pkrtz(a, b));
}

// ---------------------------------------------------------------- prep
__global__ __launch_bounds__(256)
void prep(const float* __restrict__ X,
          const float* __restrict__ Wq, const float* __restrict__ Wk,
          const float* __restrict__ Wv,
          bf16_t* __restrict__ Xb,
          bf16_t* __restrict__ Tq, bf16_t* __restrict__ Tk,
          bf16_t* __restrict__ Tv, float* __restrict__ stats)
{
    int z = blockIdx.z;
    int tid = threadIdx.x;
    if (z < 3) {
        const float* W = (z == 0) ? Wq : (z == 1) ? Wk : Wv;
        bf16_t* T = (z == 0) ? Tq : (z == 1) ? Tk : Tv;
        __shared__ bf16_t t[64][65];
        int x0 = blockIdx.x * 64, y0 = blockIdx.y * 64;
        int tx = tid & 63, ty = tid >> 6;
        for (int i = ty; i < 64; i += 4)
            t[i][tx] = (bf16_t)W[(size_t)(y0 + i) * Cdim + x0 + tx];
        __syncthreads();
        for (int i = ty; i < 64; i += 4)
            T[(size_t)(x0 + i) * Cdim + y0 + tx] = t[tx][i];
    } else {
        int bi = blockIdx.y * 16 + blockIdx.x;          // 0..255
        if (bi == 0 && tid < 4) stats[tid] = 0.0f;
        const float4* Xv = (const float4*)X;
#pragma unroll
        for (int k = 0; k < 16; k++) {
            int i = bi * 4096 + k * 256 + tid;          // 1M float4 total
            float4 v = Xv[i];
            bf16x4 o = { (bf16_t)v.x, (bf16_t)v.y, (bf16_t)v.z, (bf16_t)v.w };
            *(bf16x4*)(Xb + (size_t)i * 4) = o;
        }
    }
}

// ---------------------------------------------------------------- QKV GEMM
// m97 structure: 128x128 tile, BK=32, unpadded LDS, global_load_lds width 16.
// z==0: Q pre-scaled by SCLQ. z==1: K. z==2: V -> Vt[b][h][d][s].
__global__ __launch_bounds__(256)
void gemm_qkv(const bf16_t* __restrict__ X,
              const bf16_t* __restrict__ Wt0, const bf16_t* __restrict__ Wt1,
              const bf16_t* __restrict__ Wt2,
              const float* __restrict__ b0, const float* __restrict__ b1,
              const float* __restrict__ b2,
              f16_t* __restrict__ O0, f16_t* __restrict__ O1, f16_t* __restrict__ O2v)
{
    int z = blockIdx.z;
    const bf16_t* Wt = (z == 0) ? Wt0 : (z == 1) ? Wt1 : Wt2;
    const float* bias = (z == 0) ? b0 : (z == 1) ? b1 : b2;
    float scl = (z == 0) ? SCLQ : 1.0f;

    constexpr int Kd = 1024, Nd = 1024;
    __shared__ __align__(16) bf16_t As[128 * 32];
    __shared__ __align__(16) bf16_t Bs[128 * 32];

    int tid = threadIdx.x;
    int wave = tid >> 6, lane = tid & 63, quad = lane >> 4, l16 = lane & 15;
    int wm = (wave & 1) * 64, wn = (wave >> 1) * 64;
    int m0 = blockIdx.y * 128, n0 = blockIdx.x * 128;

    f32x4 acc[4][4] = {};

    int e0 = wave * 512 + lane * 8;
    int r0 = e0 >> 5, c0 = e0 & 31;
    int e1 = e0 + 2048;
    int r1 = e1 >> 5, c1 = e1 & 31;
    const bf16_t* Ag = X + (size_t)m0 * Kd;
    const bf16_t* Bg = Wt + (size_t)n0 * Kd;
    bf16_t* AsW0 = As + wave * 512;
    bf16_t* AsW1 = As + 2048 + wave * 512;
    bf16_t* BsW0 = Bs + wave * 512;
    bf16_t* BsW1 = Bs + 2048 + wave * 512;

    for (int k0 = 0; k0 < Kd; k0 += 32) {
        gload16(Ag + (size_t)r0 * Kd + k0 + c0, AsW0);
        gload16(Ag + (size_t)r1 * Kd + k0 + c1, AsW1);
        gload16(Bg + (size_t)r0 * Kd + k0 + c0, BsW0);
        gload16(Bg + (size_t)r1 * Kd + k0 + c1, BsW1);
        __syncthreads();

        bf16x8 af[4], bfr[4];
#pragma unroll
        for (int i = 0; i < 4; i++)
            af[i] = *(const bf16x8*)&As[(wm + i * 16 + l16) * 32 + quad * 8];
#pragma unroll
        for (int i = 0; i < 4; i++)
            bfr[i] = *(const bf16x8*)&Bs[(wn + i * 16 + l16) * 32 + quad * 8];
#pragma unroll
        for (int mt = 0; mt < 4; mt++)
#pragma unroll
            for (int nt = 0; nt < 4; nt++)
                acc[mt][nt] = __builtin_amdgcn_mfma_f32_16x16x32_bf16(
                    af[mt], bfr[nt], acc[mt][nt], 0, 0, 0);
        __syncthreads();
    }

    if (z < 2) {
        f16_t* Og = (z == 0) ? O0 : O1;
#pragma unroll
        for (int nt = 0; nt < 4; nt++) {
            int col = n0 + wn + nt * 16 + l16;
            float bv = bias[col];
#pragma unroll
            for (int mt = 0; mt < 4; mt++) {
                int row = m0 + wm + mt * 16 + quad * 4;
#pragma unroll
                for (int r = 0; r < 4; r++)
                    Og[(size_t)(row + r) * Nd + col] = (f16_t)((acc[mt][nt][r] + bv) * scl);
            }
        }
    } else {
        int bb = m0 >> 11;
#pragma unroll
        for (int nt = 0; nt < 4; nt++) {
            int col = n0 + wn + nt * 16 + l16;
            float bv = bias[col];
            int h = col >> 6, d = col & 63;
            f16_t* vbase = O2v + (((size_t)(bb * Hn + h) * Dh + d) << 11);
#pragma unroll
            for (int mt = 0; mt < 4; mt++) {
                int row = m0 + wm + mt * 16 + quad * 4;
                int s = row & (Seq - 1);
                f16x4 pk;
#pragma unroll
                for (int r = 0; r < 4; r++) pk[r] = (f16_t)(acc[mt][nt][r] + bv);
                *(f16x4*)(vbase + s) = pk;
            }
        }
    }
}

// ---------------------------------------------------------------- attention
// 512 blocks; block handles paired q-tiles (pA=p, pB=31-p) -> each wave owns
// 32 q rows; staged K/V tiles feed BOTH sides (kf/vf loaded once, 2 MFMA).
// Dbuf LDS + reg prefetch. Offset-free exp2 softmax. A-diagonal inline
// (block-uniform), B-diagonal peeled. Epilogue: resid bf16 + LN stats.
__global__ __launch_bounds__(256)
void attn8(const f16_t* __restrict__ Q, const f16_t* __restrict__ K,
           const f16_t* __restrict__ Vt, const float* __restrict__ X,
           bf16_t* __restrict__ R, float* __restrict__ stats)
{
    int id = blockIdx.x;
    int c = id & 7;            // XCD slot
    int r8 = id >> 3;          // 0..63
    int g = r8 & 3;
    int p = r8 >> 2;           // 0..15, small p = heavy block, dispatched first
    int bh = (g << 3) | c;
    int b = bh >> 4, h = bh & 15;
    int pA = p, pB = 31 - p;   // pA < pB always

    int tid = threadIdx.x;
    int w = tid >> 6, lane = tid & 63, quad = lane >> 4, l16 = lane & 15;
    size_t bS = (size_t)b * Seq;

    __shared__ f16_t Ks[2][64][72];   // [buf][kv][d]
    __shared__ f16_t Vs[2][64][72];   // [buf][d][kv]

    const f16_t* Kg = K + bS * Udim + h * Dh;
    const f16_t* Vg = Vt + ((size_t)(b * Hn + h)) * Dh * Seq;

    int sr = tid >> 2, sc = (tid & 3) * 16;
    int qA = pA * 64 + w * 16 + l16;
    int qB = pB * 64 + w * 16 + l16;

    f16x8 qfA[2], qfB[2];
    {
        const f16_t* QpA = Q + (bS + qA) * Udim + h * Dh;
        const f16_t* QpB = Q + (bS + qB) * Udim + h * Dh;
#pragma unroll
        for (int s = 0; s < 2; s++) {
            qfA[s] = *(const f16x8*)(QpA + s * 32 + quad * 8);
            qfB[s] = *(const f16x8*)(QpB + s * 32 + quad * 8);
        }
    }

    f32x4 OA[4] = {}, OB[4] = {};
    float lsA = 0.0f, lsB = 0.0f;

    const f16_t* kp = Kg + (size_t)sr * Udim + sc;
    const f16_t* vp = Vg + (size_t)sr * Seq + sc;

    // preload tile 0 into buf 0
    {
        f16x8 k0 = *(const f16x8*)kp;
        f16x8 k1 = *(const f16x8*)(kp + 8);
        f16x8 v0 = *(const f16x8*)vp;
        f16x8 v1 = *(const f16x8*)(vp + 8);
        *(f16x8*)&Ks[0][sr][sc] = k0;
        *(f16x8*)&Ks[0][sr][sc + 8] = k1;
        *(f16x8*)&Vs[0][sr][sc] = v0;
        *(f16x8*)&Vs[0][sr][sc + 8] = v1;
        kp += (size_t)64 * Udim;
        vp += 64;
    }
    __syncthreads();

    int buf = 0;
    for (int i = 0; i < pB; i++) {
        // prefetch tile i+1 (always exists: i+1 <= pB)
        f16x8 nk0 = *(const f16x8*)kp;
        f16x8 nk1 = *(const f16x8*)(kp + 8);
        f16x8 nv0 = *(const f16x8*)vp;
        f16x8 nv1 = *(const f16x8*)(vp + 8);
        kp += (size_t)64 * Udim;
        vp += 64;

        bool aFull = (i < pA);
        bool aDiag = (i == pA);

        // ---- B side: S^T, mask-free
        f16x4 pfB[4];
        {
            f32x4 stB[4];
#pragma unroll
            for (int t = 0; t < 4; t++) {
                f32x4 a = {};
#pragma unroll
                for (int s = 0; s < 2; s++) {
                    f16x8 kf = *(const f16x8*)&Ks[buf][t * 16 + l16][s * 32 + quad * 8];
                    a = __builtin_amdgcn_mfma_f32_16x16x32_f16(kf, qfB[s], a, 0, 0, 0);
                }
                stB[t] = a;
            }
#pragma unroll
            for (int t = 0; t < 4; t++) {
                float p0 = exp2f(stB[t][0]);
                float p1 = exp2f(stB[t][1]);
                float p2 = exp2f(stB[t][2]);
                float p3 = exp2f(stB[t][3]);
                lsB += (p0 + p1) + (p2 + p3);
                f16x2 lo = pkrtz(p0, p1);
                f16x2 hi = pkrtz(p2, p3);
                pfB[t][0] = lo[0]; pfB[t][1] = lo[1];
                pfB[t][2] = hi[0]; pfB[t][3] = hi[1];
            }
        }

        // ---- A side
        f16x4 pfA[4];
        if (aFull) {
            f32x4 stA[4];
#pragma unroll
            for (int t = 0; t < 4; t++) {
                f32x4 a = {};
#pragma unroll
                for (int s = 0; s < 2; s++) {
                    f16x8 kf = *(const f16x8*)&Ks[buf][t * 16 + l16][s * 32 + quad * 8];
                    a = __builtin_amdgcn_mfma_f32_16x16x32_f16(kf, qfA[s], a, 0, 0, 0);
                }
                stA[t] = a;
            }
#pragma unroll
            for (int t = 0; t < 4; t++) {
                float p0 = exp2f(stA[t][0]);
                float p1 = exp2f(stA[t][1]);
                float p2 = exp2f(stA[t][2]);
                float p3 = exp2f(stA[t][3]);
                lsA += (p0 + p1) + (p2 + p3);
                f16x2 lo = pkrtz(p0, p1);
                f16x2 hi = pkrtz(p2, p3);
                pfA[t][0] = lo[0]; pfA[t][1] = lo[1];
                pfA[t][2] = hi[0]; pfA[t][3] = hi[1];
            }
        } else if (aDiag) {
            int kv0 = i * 64;
#pragma unroll
            for (int t = 0; t < 4; t++) {
                if (t <= w) {   // wave-uniform: tiles above diagonal fully masked
                    f32x4 a = {};
#pragma unroll
                    for (int s = 0; s < 2; s++) {
                        f16x8 kf = *(const f16x8*)&Ks[buf][t * 16 + l16][s * 32 + quad * 8];
                        a = __builtin_amdgcn_mfma_f32_16x16x32_f16(kf, qfA[s], a, 0, 0, 0);
                    }
#pragma unroll
                    for (int r = 0; r < 4; r++) {
                        float sv = a[r];
                        if (kv0 + t * 16 + quad * 4 + r > qA) sv = -1e30f;  // causal
                        float pv = exp2f(sv);
                        lsA += pv;
                        pfA[t][r] = (f16_t)pv;
                    }
                }
            }
        }

        // ---- PV: vf loaded once, used for both sides
#pragma unroll
        for (int t = 0; t < 4; t++) {
            bool aUse = aFull || (aDiag && t <= w);
#pragma unroll
            for (int dt = 0; dt < 4; dt++) {
                f16x4 vf = *(const f16x4*)&Vs[buf][dt * 16 + l16][t * 16 + quad * 4];
                OB[dt] = __builtin_amdgcn_mfma_f32_16x16x16f16(vf, pfB[t], OB[dt], 0, 0, 0);
                if (aUse)
                    OA[dt] = __builtin_amdgcn_mfma_f32_16x16x16f16(vf, pfA[t], OA[dt], 0, 0, 0);
            }
        }

        // commit prefetched tile
        *(f16x8*)&Ks[buf ^ 1][sr][sc] = nk0;
        *(f16x8*)&Ks[buf ^ 1][sr][sc + 8] = nk1;
        *(f16x8*)&Vs[buf ^ 1][sr][sc] = nv0;
        *(f16x8*)&Vs[buf ^ 1][sr][sc + 8] = nv1;
        __syncthreads();
        buf ^= 1;
    }

    // ---- peeled B diagonal tile (kv0 = pB*64), t<=w only (wave-uniform)
    {
        int kv0 = pB * 64;
#pragma unroll
        for (int t = 0; t < 4; t++) {
            if (t <= w) {
                f32x4 a = {};
#pragma unroll
                for (int s = 0; s < 2; s++) {
                    f16x8 kf = *(const f16x8*)&Ks[buf][t * 16 + l16][s * 32 + quad * 8];
                    a = __builtin_amdgcn_mfma_f32_16x16x32_f16(kf, qfB[s], a, 0, 0, 0);
                }
                f16x4 pfd;
#pragma unroll
                for (int r = 0; r < 4; r++) {
                    float sv = a[r];
                    if (kv0 + t * 16 + quad * 4 + r > qB) sv = -1e30f;  // causal
                    float pv = exp2f(sv);
                    lsB += pv;
                    pfd[r] = (f16_t)pv;
                }
#pragma unroll
                for (int dt = 0; dt < 4; dt++) {
                    f16x4 vf = *(const f16x4*)&Vs[buf][dt * 16 + l16][t * 16 + quad * 4];
                    OB[dt] = __builtin_amdgcn_mfma_f32_16x16x16f16(vf, pfd, OB[dt], 0, 0, 0);
                }
            }
        }
    }

    lsA += __shfl_xor(lsA, 16);
    lsA += __shfl_xor(lsA, 32);
    lsB += __shfl_xor(lsB, 16);
    lsB += __shfl_xor(lsB, 32);
    float invA = 1.0f / lsA;
    float invB = 1.0f / lsB;

    float s_acc = 0.0f, ss_acc = 0.0f;
    {
        const float* XpA = X + (bS + qA) * Udim + h * Dh;
        bf16_t* RpA = R + (bS + qA) * Udim + h * Dh;
        const float* XpB = X + (bS + qB) * Udim + h * Dh;
        bf16_t* RpB = R + (bS + qB) * Udim + h * Dh;
#pragma unroll
        for (int dt = 0; dt < 4; dt++) {
            f32x4 xa = *(const f32x4*)(XpA + dt * 16 + quad * 4);
            f32x4 oa = OA[dt] * invA + xa;
            f32x4 xb = *(const f32x4*)(XpB + dt * 16 + quad * 4);
            f32x4 ob = OB[dt] * invB + xb;
            bf16x4 pa, pb;
#pragma unroll
            for (int r = 0; r < 4; r++) {
                pa[r] = (bf16_t)oa[r];
                pb[r] = (bf16_t)ob[r];
                s_acc += oa[r] + ob[r];
                ss_acc += oa[r] * oa[r] + ob[r] * ob[r];
            }
            *(bf16x4*)(RpA + dt * 16 + quad * 4) = pa;
            *(bf16x4*)(RpB + dt * 16 + quad * 4) = pb;
        }
    }

#pragma unroll
    for (int o = 1; o < 64; o <<= 1) {
        s_acc += __shfl_xor(s_acc, o);
        ss_acc += __shfl_xor(ss_acc, o);
    }
    __shared__ float red[8];
    if (lane == 0) { red[w] = s_acc; red[4 + w] = ss_acc; }
    __syncthreads();
    if (tid == 0) {
        atomicAdd(&stats[b], red[0] + red[1] + red[2] + red[3]);
        atomicAdd(&stats[2 + b], red[4] + red[5] + red[6] + red[7]);
    }
}

// ---------------------------------------------------------------- LN apply
__global__ __launch_bounds__(256)
void ln_norm(const bf16_t* __restrict__ R, const float* __restrict__ gamma,
             const float* __restrict__ beta, const float* __restrict__ stats,
             float* __restrict__ out)
{
    constexpr float invN = 1.0f / (float)PerBatch;
    float mu[2], inv[2];
#pragma unroll
    for (int b = 0; b < 2; b++) {
        float m = stats[b] * invN;
        float var = stats[2 + b] * invN - m * m;
        mu[b] = m;
        inv[b] = rsqrtf(var + 1e-5f);
    }
    int i = blockIdx.x * 256 + threadIdx.x;      // over 8-elem groups, 512K
    int f = i * 8;
    int b = f >> 21;
    int su = f & (PerBatch - 1);
    bf16x8 rv = *(const bf16x8*)(R + f);
    float4 g0 = *(const float4*)(gamma + su);
    float4 g1 = *(const float4*)(gamma + su + 4);
    float4 be0 = *(const float4*)(beta + su);
    float4 be1 = *(const float4*)(beta + su + 4);
    float4 o0, o1;
    o0.x = ((float)rv[0] - mu[b]) * inv[b] * g0.x + be0.x;
    o0.y = ((float)rv[1] - mu[b]) * inv[b] * g0.y + be0.y;
    o0.z = ((float)rv[2] - mu[b]) * inv[b] * g0.z + be0.z;
    o0.w = ((float)rv[3] - mu[b]) * inv[b] * g0.w + be0.w;
    o1.x = ((float)rv[4] - mu[b]) * inv[b] * g1.x + be1.x;
    o1.y = ((float)rv[5] - mu[b]) * inv[b] * g1.y + be1.y;
    o1.z = ((float)rv[6] - mu[b]) * inv[b] * g1.z + be1.z;
    o1.w = ((float)rv[7] - mu[b]) * inv[b] * g1.w + be1.w;
    *(float4*)(out + f) = o0;
    *(float4*)(out + f + 4) = o1;
}

// ---------------------------------------------------------------- launch
extern "C" void kernel_launch(void* const* d_in, const int* in_sizes, int n_in,
                              void* d_out, int out_size, void* d_ws, size_t ws_size,
                              hipStream_t stream)
{
    const float* X     = (const float*)d_in[0];
    const float* Wq    = (const float*)d_in[1];
    const float* bq    = (const float*)d_in[2];
    const float* Wk    = (const float*)d_in[3];
    const float* bk    = (const float*)d_in[4];
    const float* Wv    = (const float*)d_in[5];
    const float* bv    = (const float*)d_in[6];
    const float* gamma = (const float*)d_in[7];
    const float* beta  = (const float*)d_in[8];
    float* out = (float*)d_out;

    char* ws = (char*)d_ws;
    size_t off = 0;
    auto alloc = [&](size_t bytes) -> void* {
        void* p = ws + off;
        off += (bytes + 255) & ~(size_t)255;
        return p;
    };
    bf16_t* Xb = (bf16_t*)alloc((size_t)Mrows * Cdim * 2);
    bf16_t* Tq = (bf16_t*)alloc((size_t)Cdim * Udim * 2);
    bf16_t* Tk = (bf16_t*)alloc((size_t)Cdim * Udim * 2);
    bf16_t* Tv = (bf16_t*)alloc((size_t)Cdim * Udim * 2);
    f16_t*  Qb = (f16_t*)alloc((size_t)Mrows * Udim * 2);
    f16_t*  Kb = (f16_t*)alloc((size_t)Mrows * Udim * 2);
    f16_t*  Vtb = (f16_t*)alloc((size_t)Mrows * Udim * 2);
    bf16_t* Rb = (bf16_t*)alloc((size_t)Mrows * Udim * 2);
    float*  stats = (float*)alloc(4 * sizeof(float));

    prep<<<dim3(16, 16, 4), 256, 0, stream>>>(X, Wq, Wk, Wv, Xb, Tq, Tk, Tv, stats);
    gemm_qkv<<<dim3(8, 32, 3), 256, 0, stream>>>(Xb, Tq, Tk, Tv, bq, bk, bv, Qb, Kb, Vtb);
    attn8<<<dim3(512), 256, 0, stream>>>(Qb, Kb, Vtb, X, Rb, stats);
    ln_norm<<<dim3(2048), 256, 0, stream>>>(Rb, gamma, beta, stats, out);
}